// Round 2
// baseline (475.945 us; speedup 1.0000x reference)
//
#include <hip/hip_runtime.h>
#include <hip/hip_bf16.h>
#include <math.h>

// Problem constants (from reference)
#define B_SZ 32
#define T_SZ 4096
#define DV   512   // DIM_VECT
#define DA   256   // DIM_ATTN
#define DK   512   // DIM_ATTN_BID (matrix feature dim)

typedef __attribute__((ext_vector_type(8))) __bf16 bf16x8;
typedef __attribute__((ext_vector_type(4))) __bf16 bf16x4;
typedef __attribute__((ext_vector_type(4))) float  f32x4;

// Lengths may arrive as int32 or int64. Valid lengths are in [1, 4096], so for
// int64 little-endian p[1]==0; for int32 p[1] is a real length >= 1.
__device__ inline int get_len(const int* __restrict__ p, int b) {
    return (p[1] == 0) ? p[2 * b] : p[b];
}

// ---------------------------------------------------------------------------
// Kernel 0: convert W_mat [DA, DK] f32 -> bf16 (natural [a][k] layout)
// ---------------------------------------------------------------------------
__global__ void conv_wmat_kernel(const float* __restrict__ w, __bf16* __restrict__ out) {
    int i = (blockIdx.x * 256 + threadIdx.x) * 4;
    float4 v = *(const float4*)(w + i);
    bf16x4 o;
    o[0] = (__bf16)v.x; o[1] = (__bf16)v.y; o[2] = (__bf16)v.z; o[3] = (__bf16)v.w;
    *(bf16x4*)(out + i) = o;
}

// ---------------------------------------------------------------------------
// Kernel 1: t1[b,a] = dot(vector[b,:], W_vec[a,:])  (f32), and zero rep area
// ---------------------------------------------------------------------------
__global__ void t1_kernel(const float* __restrict__ vector, const float* __restrict__ wvec,
                          float* __restrict__ t1, float* __restrict__ rep) {
    int b = blockIdx.x, tid = threadIdx.x;
    __shared__ float sv[DV];
    sv[tid]       = vector[b * DV + tid];
    sv[tid + 256] = vector[b * DV + tid + 256];
    rep[b * DV + tid]       = 0.f;
    rep[b * DV + tid + 256] = 0.f;
    __syncthreads();
    const float4* w  = (const float4*)(wvec + (size_t)tid * DV);
    const float4* s4 = (const float4*)sv;
    float acc = 0.f;
#pragma unroll 8
    for (int k = 0; k < DV / 4; k++) {
        float4 wv = w[k]; float4 xv = s4[k];
        acc += wv.x * xv.x + wv.y * xv.y + wv.z * xv.z + wv.w * xv.w;
    }
    t1[b * DA + tid] = acc;
}

// ---------------------------------------------------------------------------
// Kernel 2: fused logits — barrier-free direct-from-global MFMA GEMM.
// Block: 64 t-rows, 4 waves; wave w covers 64t x 64a (a-quarter w).
// Fragment layout (verified round 1): idx = lane&15, k = (lane>>4)*8 + j —
// 8 consecutive k elems => A frag = 2x float4 (convert), B frag = 1x uint4.
// No LDS in K-loop, no __syncthreads in K-loop, 2-stage register pipeline.
// ---------------------------------------------------------------------------
#define TM 64

__global__ __launch_bounds__(256) void logits_kernel(
    const float* __restrict__ matrix, const __bf16* __restrict__ wmat,
    const float* __restrict__ t1, const float* __restrict__ wattn,
    const int* __restrict__ lens, float* __restrict__ logits) {
    int b  = blockIdx.y;
    int t0 = blockIdx.x * TM;
    int len = get_len(lens, b);
    if (t0 >= len) return;   // masked rows never read downstream

    __shared__ float s_t1[DA];
    __shared__ float s_wa[DA];
    __shared__ float s_logit[TM];

    int tid = threadIdx.x;
    s_t1[tid] = t1[b * DA + tid];
    s_wa[tid] = wattn[tid];
    if (tid < TM) s_logit[tid] = 0.f;
    __syncthreads();

    int wave = tid >> 6, lane = tid & 63;
    int col  = lane & 15;            // m-row (A) / a-col (B) within 16x16 tile
    int koff = (lane >> 4) * 8;      // k sub-offset

    const float*  Arow[4];
    const __bf16* Brow[4];
#pragma unroll
    for (int mt = 0; mt < 4; mt++)
        Arow[mt] = matrix + ((size_t)b * T_SZ + t0 + mt * 16 + col) * DK + koff;
#pragma unroll
    for (int nt = 0; nt < 4; nt++)
        Brow[nt] = wmat + (size_t)(wave * 64 + nt * 16 + col) * DK + koff;

    f32x4 acc[4][4];
    f32x4 zero = {0.f, 0.f, 0.f, 0.f};
#pragma unroll
    for (int i = 0; i < 4; i++)
#pragma unroll
        for (int j = 0; j < 4; j++) acc[i][j] = zero;

    // 2-stage pipeline: preload k-step 0
    float4 a0[4], a1[4];
    uint4  bv[4];
#pragma unroll
    for (int mt = 0; mt < 4; mt++) {
        a0[mt] = *(const float4*)(Arow[mt]);
        a1[mt] = *(const float4*)(Arow[mt] + 4);
    }
#pragma unroll
    for (int nt = 0; nt < 4; nt++) bv[nt] = *(const uint4*)(Brow[nt]);

    for (int ks = 0; ks < DK / 32; ks++) {
        bf16x8 af[4], bfb[4];
#pragma unroll
        for (int mt = 0; mt < 4; mt++) {
            bf16x8 v;
            v[0] = (__bf16)a0[mt].x; v[1] = (__bf16)a0[mt].y;
            v[2] = (__bf16)a0[mt].z; v[3] = (__bf16)a0[mt].w;
            v[4] = (__bf16)a1[mt].x; v[5] = (__bf16)a1[mt].y;
            v[6] = (__bf16)a1[mt].z; v[7] = (__bf16)a1[mt].w;
            af[mt] = v;
        }
#pragma unroll
        for (int nt = 0; nt < 4; nt++) bfb[nt] = *(bf16x8*)&bv[nt];

        if (ks < DK / 32 - 1) {
            int k1 = (ks + 1) * 32;
#pragma unroll
            for (int mt = 0; mt < 4; mt++) {
                a0[mt] = *(const float4*)(Arow[mt] + k1);
                a1[mt] = *(const float4*)(Arow[mt] + k1 + 4);
            }
#pragma unroll
            for (int nt = 0; nt < 4; nt++) bv[nt] = *(const uint4*)(Brow[nt] + k1);
        }

#pragma unroll
        for (int mt = 0; mt < 4; mt++)
#pragma unroll
            for (int nt = 0; nt < 4; nt++)
                acc[mt][nt] = __builtin_amdgcn_mfma_f32_16x16x32_bf16(af[mt], bfb[nt], acc[mt][nt], 0, 0, 0);
    }

    // Epilogue: v = W_attn[a]*relu(t1[a]+t2), reduce over this wave's a-quarter.
    // C/D layout: col = lane&15, row = (lane>>4)*4 + reg
    int rg = lane >> 4;
#pragma unroll
    for (int mt = 0; mt < 4; mt++) {
#pragma unroll
        for (int r = 0; r < 4; r++) {
            float v = 0.f;
#pragma unroll
            for (int nt = 0; nt < 4; nt++) {
                int a = wave * 64 + nt * 16 + col;
                float x = acc[mt][nt][r] + s_t1[a];
                v += s_wa[a] * fmaxf(x, 0.f);
            }
#pragma unroll
            for (int off = 1; off < 16; off <<= 1) v += __shfl_xor(v, off, 64);
            if (col == 0) atomicAdd(&s_logit[mt * 16 + rg * 4 + r], v);
        }
    }
    __syncthreads();
    if (tid < TM) logits[(size_t)b * T_SZ + t0 + tid] = s_logit[tid];
}

// ---------------------------------------------------------------------------
// Kernel 3: per-row softmax, single global read pass (1024 threads, 4 vals/thr
// in registers). Row max == global max after normalization (shift invariance).
// ---------------------------------------------------------------------------
__global__ __launch_bounds__(1024) void softmax_kernel(const int* __restrict__ lens,
                                                       float* __restrict__ attn) {
    int b = blockIdx.x, tid = threadIdx.x;
    int len = get_len(lens, b);
    float* row = attn + (size_t)b * T_SZ;
    __shared__ float sred[16];

    float r[4];
#pragma unroll
    for (int i = 0; i < 4; i++) r[i] = row[tid + i * 1024];

    float m = -1e30f;
#pragma unroll
    for (int i = 0; i < 4; i++)
        if (tid + i * 1024 < len) m = fmaxf(m, r[i]);
#pragma unroll
    for (int off = 32; off; off >>= 1) m = fmaxf(m, __shfl_xor(m, off, 64));
    if ((tid & 63) == 0) sred[tid >> 6] = m;
    __syncthreads();
    m = sred[0];
#pragma unroll
    for (int i = 1; i < 16; i++) m = fmaxf(m, sred[i]);
    __syncthreads();

    float e[4];
    float s = 0.f;
#pragma unroll
    for (int i = 0; i < 4; i++) {
        e[i] = (tid + i * 1024 < len) ? __expf(r[i] - m) : 0.f;
        s += e[i];
    }
#pragma unroll
    for (int off = 32; off; off >>= 1) s += __shfl_xor(s, off, 64);
    if ((tid & 63) == 0) sred[tid >> 6] = s;
    __syncthreads();
    s = 0.f;
#pragma unroll
    for (int i = 0; i < 16; i++) s += sred[i];
    float inv = 1.f / s;

#pragma unroll
    for (int i = 0; i < 4; i++) row[tid + i * 1024] = e[i] * inv;
}

// ---------------------------------------------------------------------------
// Kernel 4: rep[b,d] += sum_t attn[b,t] * matrix[b,t,d], length-clipped chunks,
// atomicAdd into the (pre-zeroed) rep area. TC=128 for better load balance.
// ---------------------------------------------------------------------------
#define TC 128
__global__ void rep_kernel(const float* __restrict__ matrix, const float* __restrict__ attn,
                           const int* __restrict__ lens, float* __restrict__ rep) {
    int b = blockIdx.y, c = blockIdx.x, tid = threadIdx.x;
    int len = get_len(lens, b);
    int t0 = c * TC;
    if (t0 >= len) return;
    __shared__ float sa[TC];
    if (tid < TC) sa[tid] = attn[(size_t)b * T_SZ + t0 + tid];
    __syncthreads();
    int n = min(TC, len - t0);
    const float* M = matrix + ((size_t)b * T_SZ + t0) * DK;
    float ax = 0.f, ay = 0.f;
    int d = 2 * tid;
#pragma unroll 8
    for (int t = 0; t < n; t++) {
        float w = sa[t];
        float2 mv = *(const float2*)(M + (size_t)t * DK + d);
        ax = fmaf(w, mv.x, ax);
        ay = fmaf(w, mv.y, ay);
    }
    atomicAdd(&rep[b * DV + d], ax);
    atomicAdd(&rep[b * DV + d + 1], ay);
}

// ---------------------------------------------------------------------------
extern "C" void kernel_launch(void* const* d_in, const int* in_sizes, int n_in,
                              void* d_out, int out_size, void* d_ws, size_t ws_size,
                              hipStream_t stream) {
    const float* vector = (const float*)d_in[0];
    const float* matrix = (const float*)d_in[1];
    const int*   lens   = (const int*)d_in[2];
    const float* wvec   = (const float*)d_in[3];
    const float* wmat   = (const float*)d_in[4];
    const float* wattn  = (const float*)d_in[5];

    float* rep  = (float*)d_out;            // [32, 512]
    float* attn = rep + B_SZ * DV;          // [32, 4096] logits -> in-place softmax

    float*  t1      = (float*)d_ws;                          // 32*256 f32 = 32 KB
    __bf16* wmat_bf = (__bf16*)((char*)d_ws + 32768);        // 256*512 bf16 = 256 KB

    conv_wmat_kernel<<<dim3((DA * DK) / (256 * 4)), 256, 0, stream>>>(wmat, wmat_bf);
    t1_kernel<<<dim3(B_SZ), 256, 0, stream>>>(vector, wvec, t1, rep);
    logits_kernel<<<dim3(T_SZ / TM, B_SZ), 256, 0, stream>>>(matrix, wmat_bf, t1, wattn, lens, attn);
    softmax_kernel<<<dim3(B_SZ), 1024, 0, stream>>>(lens, attn);
    rep_kernel<<<dim3(T_SZ / TC, B_SZ), 256, 0, stream>>>(matrix, attn, lens, rep);
}

// Round 3
// 416.901 us; speedup vs baseline: 1.1416x; 1.1416x over previous
//
#include <hip/hip_runtime.h>
#include <hip/hip_bf16.h>
#include <math.h>

// Problem constants (from reference)
#define B_SZ 32
#define T_SZ 4096
#define DV   512   // DIM_VECT
#define DA   256   // DIM_ATTN
#define DK   512   // DIM_ATTN_BID (matrix feature dim)

typedef __attribute__((ext_vector_type(8))) __bf16 bf16x8;
typedef __attribute__((ext_vector_type(4))) __bf16 bf16x4;
typedef __attribute__((ext_vector_type(4))) float  f32x4;

// Lengths may arrive as int32 or int64. Valid lengths are in [1, 4096], so for
// int64 little-endian p[1]==0; for int32 p[1] is a real length >= 1.
__device__ inline int get_len(const int* __restrict__ p, int b) {
    return (p[1] == 0) ? p[2 * b] : p[b];
}

// ---------------------------------------------------------------------------
// Kernel 0 (fused setup): blocks 0..127 convert W_mat f32->bf16;
// blocks 128..159 compute t1[b,a] = vector[b,:]·W_vec[a,:] and zero rep.
// ---------------------------------------------------------------------------
__global__ void setup_kernel(const float* __restrict__ wmat, __bf16* __restrict__ wmat_bf,
                             const float* __restrict__ vector, const float* __restrict__ wvec,
                             float* __restrict__ t1, float* __restrict__ rep) {
    int blk = blockIdx.x, tid = threadIdx.x;
    if (blk < 128) {
        int i = (blk * 256 + tid) * 4;
        float4 v = *(const float4*)(wmat + i);
        bf16x4 o;
        o[0] = (__bf16)v.x; o[1] = (__bf16)v.y; o[2] = (__bf16)v.z; o[3] = (__bf16)v.w;
        *(bf16x4*)(wmat_bf + i) = o;
        return;
    }
    int b = blk - 128;
    __shared__ float sv[DV];
    sv[tid]       = vector[b * DV + tid];
    sv[tid + 256] = vector[b * DV + tid + 256];
    rep[b * DV + tid]       = 0.f;
    rep[b * DV + tid + 256] = 0.f;
    __syncthreads();
    const float4* w  = (const float4*)(wvec + (size_t)tid * DV);
    const float4* s4 = (const float4*)sv;
    float acc = 0.f;
#pragma unroll 8
    for (int k = 0; k < DV / 4; k++) {
        float4 wv = w[k]; float4 xv = s4[k];
        acc += wv.x * xv.x + wv.y * xv.y + wv.z * xv.z + wv.w * xv.w;
    }
    t1[b * DA + tid] = acc;
}

// ---------------------------------------------------------------------------
// Kernel 1: fused logits. Block = 64 t-rows x 256 a-cols, 4 waves.
// A (matrix) staged f32->bf16 into double-buffered LDS with fully-coalesced
// loads (16 lanes/row x 16B = 1KB contiguous per instruction). B (wmat bf16,
// L2-resident) loaded direct-to-register, prefetched one k-step ahead.
// BK=64 -> 8 k-steps, ONE barrier per step. LDS row stride 72 bf16 = 144B
// (16B-aligned for ds_read_b128, 4-bank rotation per row).
// ---------------------------------------------------------------------------
#define TM  64
#define LDA 72

__global__ __launch_bounds__(256) void logits_kernel(
    const float* __restrict__ matrix, const __bf16* __restrict__ wmat,
    const float* __restrict__ t1, const float* __restrict__ wattn,
    const int* __restrict__ lens, float* __restrict__ logits) {
    int b  = blockIdx.y;
    int t0 = blockIdx.x * TM;
    int len = get_len(lens, b);
    if (t0 >= len) return;   // masked rows never read downstream

    __shared__ __bf16 sA[2][TM][LDA];    // 18.4 KB
    __shared__ float s_t1[DA];
    __shared__ float s_wa[DA];
    __shared__ float s_logit[TM];

    int tid = threadIdx.x;
    s_t1[tid] = t1[b * DA + tid];
    s_wa[tid] = wattn[tid];
    if (tid < TM) s_logit[tid] = 0.f;

    int wave = tid >> 6, lane = tid & 63;
    int col  = lane & 15;            // t-row (A) / a-col (B) within 16x16 tile
    int koff = (lane >> 4) * 8;      // k sub-offset (bf16 elems)

    // staging assignment: 16 lanes per row, 4 floats (16B) per lane
    int srow = tid >> 4;             // 0..15 (rows srow, srow+16, +32, +48)
    int soff = (tid & 15) * 4;       // k index 0..60

    const float* Abase = matrix + ((size_t)b * T_SZ + t0) * DK;
    const __bf16* Bp[4];
#pragma unroll
    for (int nt = 0; nt < 4; nt++)
        Bp[nt] = wmat + (size_t)(wave * 64 + nt * 16 + col) * DK + koff;

    f32x4 acc[4][4];
    f32x4 zero = {0.f, 0.f, 0.f, 0.f};
#pragma unroll
    for (int i = 0; i < 4; i++)
#pragma unroll
        for (int j = 0; j < 4; j++) acc[i][j] = zero;

    // prologue: stage k-step 0 into buffer 0, prefetch B for step 0
    {
#pragma unroll
        for (int r = 0; r < 4; r++) {
            float4 v = *(const float4*)(Abase + (size_t)(srow + r * 16) * DK + soff);
            bf16x4 o;
            o[0] = (__bf16)v.x; o[1] = (__bf16)v.y; o[2] = (__bf16)v.z; o[3] = (__bf16)v.w;
            *(bf16x4*)&sA[0][srow + r * 16][soff] = o;
        }
    }
    uint4 pb[8];
#pragma unroll
    for (int s = 0; s < 2; s++)
#pragma unroll
        for (int nt = 0; nt < 4; nt++)
            pb[s * 4 + nt] = *(const uint4*)(Bp[nt] + s * 32);

    __syncthreads();

    for (int ks = 0; ks < 8; ks++) {
        int buf = ks & 1;
        // prefetch next step (A raw f32 into regs, B into regs)
        float4 na[4];
        uint4  nb[8];
        if (ks < 7) {
            int k1 = (ks + 1) * 64;
#pragma unroll
            for (int r = 0; r < 4; r++)
                na[r] = *(const float4*)(Abase + (size_t)(srow + r * 16) * DK + k1 + soff);
#pragma unroll
            for (int s = 0; s < 2; s++)
#pragma unroll
                for (int nt = 0; nt < 4; nt++)
                    nb[s * 4 + nt] = *(const uint4*)(Bp[nt] + k1 + s * 32);
        }
        // A fragments from LDS
        bf16x8 af[2][4];
#pragma unroll
        for (int s = 0; s < 2; s++)
#pragma unroll
            for (int mt = 0; mt < 4; mt++)
                af[s][mt] = *(const bf16x8*)&sA[buf][mt * 16 + col][s * 32 + koff];
        // 32 MFMAs
#pragma unroll
        for (int s = 0; s < 2; s++)
#pragma unroll
            for (int mt = 0; mt < 4; mt++)
#pragma unroll
                for (int nt = 0; nt < 4; nt++)
                    acc[mt][nt] = __builtin_amdgcn_mfma_f32_16x16x32_bf16(
                        af[s][mt], *(bf16x8*)&pb[s * 4 + nt], acc[mt][nt], 0, 0, 0);
        // convert + write next A tile into the other buffer; rotate B regs
        if (ks < 7) {
#pragma unroll
            for (int r = 0; r < 4; r++) {
                bf16x4 o;
                o[0] = (__bf16)na[r].x; o[1] = (__bf16)na[r].y;
                o[2] = (__bf16)na[r].z; o[3] = (__bf16)na[r].w;
                *(bf16x4*)&sA[buf ^ 1][srow + r * 16][soff] = o;
            }
#pragma unroll
            for (int i = 0; i < 8; i++) pb[i] = nb[i];
        }
        __syncthreads();
    }

    // Epilogue: v = W_attn[a]*relu(t1[a]+t2), reduce over this wave's a-quarter.
    // C/D layout (verified): col = lane&15, row = (lane>>4)*4 + reg
    int rg = lane >> 4;
#pragma unroll
    for (int mt = 0; mt < 4; mt++) {
#pragma unroll
        for (int r = 0; r < 4; r++) {
            float v = 0.f;
#pragma unroll
            for (int nt = 0; nt < 4; nt++) {
                int a = wave * 64 + nt * 16 + col;
                float x = acc[mt][nt][r] + s_t1[a];
                v += s_wa[a] * fmaxf(x, 0.f);
            }
#pragma unroll
            for (int off = 1; off < 16; off <<= 1) v += __shfl_xor(v, off, 64);
            if (col == 0) atomicAdd(&s_logit[mt * 16 + rg * 4 + r], v);
        }
    }
    __syncthreads();
    if (tid < TM) logits[(size_t)b * T_SZ + t0 + tid] = s_logit[tid];
}

// ---------------------------------------------------------------------------
// Kernel 2: per-row softmax, single global read pass (1024 threads, 4 vals/thr
// in registers). Row max == global max after normalization (shift invariance).
// ---------------------------------------------------------------------------
__global__ __launch_bounds__(1024) void softmax_kernel(const int* __restrict__ lens,
                                                       float* __restrict__ attn) {
    int b = blockIdx.x, tid = threadIdx.x;
    int len = get_len(lens, b);
    float* row = attn + (size_t)b * T_SZ;
    __shared__ float sred[16];

    float r[4];
#pragma unroll
    for (int i = 0; i < 4; i++) r[i] = row[tid + i * 1024];

    float m = -1e30f;
#pragma unroll
    for (int i = 0; i < 4; i++)
        if (tid + i * 1024 < len) m = fmaxf(m, r[i]);
#pragma unroll
    for (int off = 32; off; off >>= 1) m = fmaxf(m, __shfl_xor(m, off, 64));
    if ((tid & 63) == 0) sred[tid >> 6] = m;
    __syncthreads();
    m = sred[0];
#pragma unroll
    for (int i = 1; i < 16; i++) m = fmaxf(m, sred[i]);
    __syncthreads();

    float e[4];
    float s = 0.f;
#pragma unroll
    for (int i = 0; i < 4; i++) {
        e[i] = (tid + i * 1024 < len) ? __expf(r[i] - m) : 0.f;
        s += e[i];
    }
#pragma unroll
    for (int off = 32; off; off >>= 1) s += __shfl_xor(s, off, 64);
    if ((tid & 63) == 0) sred[tid >> 6] = s;
    __syncthreads();
    s = 0.f;
#pragma unroll
    for (int i = 0; i < 16; i++) s += sred[i];
    float inv = 1.f / s;

#pragma unroll
    for (int i = 0; i < 4; i++) row[tid + i * 1024] = e[i] * inv;
}

// ---------------------------------------------------------------------------
// Kernel 3: rep[b,d] += sum_t attn[b,t] * matrix[b,t,d]. float4 per lane
// (1KB coalesced per wave instruction); t-range split across thread halves.
// ---------------------------------------------------------------------------
#define TC 128
__global__ void rep_kernel(const float* __restrict__ matrix, const float* __restrict__ attn,
                           const int* __restrict__ lens, float* __restrict__ rep) {
    int b = blockIdx.y, c = blockIdx.x, tid = threadIdx.x;
    int len = get_len(lens, b);
    int t0 = c * TC;
    if (t0 >= len) return;
    __shared__ float sa[TC];
    if (tid < TC) sa[tid] = attn[(size_t)b * T_SZ + t0 + tid];
    __syncthreads();
    int n = min(TC, len - t0);
    int half = tid >> 7;             // 0 or 1: split t-range
    int l = tid & 127;
    int d = l * 4;
    int nh = (n + 1) >> 1;
    int tb = half ? nh : 0;
    int te = half ? n : nh;
    const float* M = matrix + ((size_t)b * T_SZ + t0) * DK;
    float a0 = 0.f, a1 = 0.f, a2 = 0.f, a3 = 0.f;
#pragma unroll 4
    for (int t = tb; t < te; t++) {
        float w = sa[t];
        float4 mv = *(const float4*)(M + (size_t)t * DK + d);
        a0 = fmaf(w, mv.x, a0); a1 = fmaf(w, mv.y, a1);
        a2 = fmaf(w, mv.z, a2); a3 = fmaf(w, mv.w, a3);
    }
    atomicAdd(&rep[b * DV + d],     a0);
    atomicAdd(&rep[b * DV + d + 1], a1);
    atomicAdd(&rep[b * DV + d + 2], a2);
    atomicAdd(&rep[b * DV + d + 3], a3);
}

// ---------------------------------------------------------------------------
extern "C" void kernel_launch(void* const* d_in, const int* in_sizes, int n_in,
                              void* d_out, int out_size, void* d_ws, size_t ws_size,
                              hipStream_t stream) {
    const float* vector = (const float*)d_in[0];
    const float* matrix = (const float*)d_in[1];
    const int*   lens   = (const int*)d_in[2];
    const float* wvec   = (const float*)d_in[3];
    const float* wmat   = (const float*)d_in[4];
    const float* wattn  = (const float*)d_in[5];

    float* rep  = (float*)d_out;            // [32, 512]
    float* attn = rep + B_SZ * DV;          // [32, 4096] logits -> in-place softmax

    float*  t1      = (float*)d_ws;                          // 32*256 f32 = 32 KB
    __bf16* wmat_bf = (__bf16*)((char*)d_ws + 32768);        // 256*512 bf16 = 256 KB

    setup_kernel<<<dim3(160), 256, 0, stream>>>(wmat, wmat_bf, vector, wvec, t1, rep);
    logits_kernel<<<dim3(T_SZ / TM, B_SZ), 256, 0, stream>>>(matrix, wmat_bf, t1, wattn, lens, attn);
    softmax_kernel<<<dim3(B_SZ), 1024, 0, stream>>>(lens, attn);
    rep_kernel<<<dim3(T_SZ / TC, B_SZ), 256, 0, stream>>>(matrix, attn, lens, rep);
}

// Round 4
// 407.899 us; speedup vs baseline: 1.1668x; 1.0221x over previous
//
#include <hip/hip_runtime.h>
#include <hip/hip_bf16.h>
#include <math.h>

// Problem constants (from reference)
#define B_SZ 32
#define T_SZ 4096
#define DV   512   // DIM_VECT
#define DA   256   // DIM_ATTN
#define DK   512   // DIM_ATTN_BID (matrix feature dim)

typedef __attribute__((ext_vector_type(8))) __bf16 bf16x8;
typedef __attribute__((ext_vector_type(4))) __bf16 bf16x4;
typedef __attribute__((ext_vector_type(4))) float  f32x4;

// Lengths may arrive as int32 or int64. Valid lengths are in [1, 4096], so for
// int64 little-endian p[1]==0; for int32 p[1] is a real length >= 1.
__device__ inline int get_len(const int* __restrict__ p, int b) {
    return (p[1] == 0) ? p[2 * b] : p[b];
}

// ---------------------------------------------------------------------------
// Kernel 0 (fused setup): blocks 0..127 convert W_mat f32->bf16;
// blocks 128..159 compute t1[b,a] = vector[b,:]·W_vec[a,:].
// ---------------------------------------------------------------------------
__global__ void setup_kernel(const float* __restrict__ wmat, __bf16* __restrict__ wmat_bf,
                             const float* __restrict__ vector, const float* __restrict__ wvec,
                             float* __restrict__ t1) {
    int blk = blockIdx.x, tid = threadIdx.x;
    if (blk < 128) {
        int i = (blk * 256 + tid) * 4;
        float4 v = *(const float4*)(wmat + i);
        bf16x4 o;
        o[0] = (__bf16)v.x; o[1] = (__bf16)v.y; o[2] = (__bf16)v.z; o[3] = (__bf16)v.w;
        *(bf16x4*)(wmat_bf + i) = o;
        return;
    }
    int b = blk - 128;
    __shared__ float sv[DV];
    sv[tid]       = vector[b * DV + tid];
    sv[tid + 256] = vector[b * DV + tid + 256];
    __syncthreads();
    const float4* w  = (const float4*)(wvec + (size_t)tid * DV);
    const float4* s4 = (const float4*)sv;
    float acc = 0.f;
#pragma unroll 8
    for (int k = 0; k < DV / 4; k++) {
        float4 wv = w[k]; float4 xv = s4[k];
        acc += wv.x * xv.x + wv.y * xv.y + wv.z * xv.z + wv.w * xv.w;
    }
    t1[b * DA + tid] = acc;
}

// ---------------------------------------------------------------------------
// Kernel 1: fused logits + block-local online-softmax partials.
// GEMM part identical to round 3 (A staged f32->bf16 into double-buffered LDS
// with fully-coalesced 1KB loads; B direct-to-register, prefetched; BK=64,
// one barrier per k-step). New epilogue: per-block local max m_blk, local
// s_blk = sum exp(l - m_blk), and partial P[d] = sum_t exp(l_t - m_blk)*M[t,d]
// (A-tile re-read from L2 — it was just loaded). Raw logits also written.
// ---------------------------------------------------------------------------
#define TM  64
#define LDA 72
#define NBLK (T_SZ / TM)   // 64 t-blocks per batch row

__global__ __launch_bounds__(256) void logits_kernel(
    const float* __restrict__ matrix, const __bf16* __restrict__ wmat,
    const float* __restrict__ t1, const float* __restrict__ wattn,
    const int* __restrict__ lens, float* __restrict__ logits,
    float* __restrict__ P, float* __restrict__ ms) {
    int b  = blockIdx.y;
    int blk = blockIdx.x;
    int t0 = blk * TM;
    int len = get_len(lens, b);
    if (t0 >= len) return;   // inactive blocks: combine kernel never reads their slots

    __shared__ __bf16 sA[2][TM][LDA];    // 18.4 KB
    __shared__ float s_t1[DA];
    __shared__ float s_wa[DA];
    __shared__ float s_logit[TM];
    __shared__ float sw[TM];

    int tid = threadIdx.x;
    s_t1[tid] = t1[b * DA + tid];
    s_wa[tid] = wattn[tid];
    if (tid < TM) s_logit[tid] = 0.f;

    int wave = tid >> 6, lane = tid & 63;
    int col  = lane & 15;            // t-row (A) / a-col (B) within 16x16 tile
    int koff = (lane >> 4) * 8;      // k sub-offset (bf16 elems)

    // staging assignment: 16 lanes per row, 4 floats (16B) per lane
    int srow = tid >> 4;             // 0..15 (rows srow, srow+16, +32, +48)
    int soff = (tid & 15) * 4;       // k index 0..60

    const float* Abase = matrix + ((size_t)b * T_SZ + t0) * DK;
    const __bf16* Bp[4];
#pragma unroll
    for (int nt = 0; nt < 4; nt++)
        Bp[nt] = wmat + (size_t)(wave * 64 + nt * 16 + col) * DK + koff;

    f32x4 acc[4][4];
    f32x4 zero = {0.f, 0.f, 0.f, 0.f};
#pragma unroll
    for (int i = 0; i < 4; i++)
#pragma unroll
        for (int j = 0; j < 4; j++) acc[i][j] = zero;

    // prologue: stage k-step 0 into buffer 0, prefetch B for step 0
#pragma unroll
    for (int r = 0; r < 4; r++) {
        float4 v = *(const float4*)(Abase + (size_t)(srow + r * 16) * DK + soff);
        bf16x4 o;
        o[0] = (__bf16)v.x; o[1] = (__bf16)v.y; o[2] = (__bf16)v.z; o[3] = (__bf16)v.w;
        *(bf16x4*)&sA[0][srow + r * 16][soff] = o;
    }
    uint4 pb[8];
#pragma unroll
    for (int s = 0; s < 2; s++)
#pragma unroll
        for (int nt = 0; nt < 4; nt++)
            pb[s * 4 + nt] = *(const uint4*)(Bp[nt] + s * 32);

    __syncthreads();

    for (int ks = 0; ks < 8; ks++) {
        int buf = ks & 1;
        float4 na[4];
        uint4  nb[8];
        if (ks < 7) {
            int k1 = (ks + 1) * 64;
#pragma unroll
            for (int r = 0; r < 4; r++)
                na[r] = *(const float4*)(Abase + (size_t)(srow + r * 16) * DK + k1 + soff);
#pragma unroll
            for (int s = 0; s < 2; s++)
#pragma unroll
                for (int nt = 0; nt < 4; nt++)
                    nb[s * 4 + nt] = *(const uint4*)(Bp[nt] + k1 + s * 32);
        }
        bf16x8 af[2][4];
#pragma unroll
        for (int s = 0; s < 2; s++)
#pragma unroll
            for (int mt = 0; mt < 4; mt++)
                af[s][mt] = *(const bf16x8*)&sA[buf][mt * 16 + col][s * 32 + koff];
#pragma unroll
        for (int s = 0; s < 2; s++)
#pragma unroll
            for (int mt = 0; mt < 4; mt++)
#pragma unroll
                for (int nt = 0; nt < 4; nt++)
                    acc[mt][nt] = __builtin_amdgcn_mfma_f32_16x16x32_bf16(
                        af[s][mt], *(bf16x8*)&pb[s * 4 + nt], acc[mt][nt], 0, 0, 0);
        if (ks < 7) {
#pragma unroll
            for (int r = 0; r < 4; r++) {
                bf16x4 o;
                o[0] = (__bf16)na[r].x; o[1] = (__bf16)na[r].y;
                o[2] = (__bf16)na[r].z; o[3] = (__bf16)na[r].w;
                *(bf16x4*)&sA[buf ^ 1][srow + r * 16][soff] = o;
            }
#pragma unroll
            for (int i = 0; i < 8; i++) pb[i] = nb[i];
        }
        __syncthreads();
    }

    // logits epilogue: v = W_attn[a]*relu(t1[a]+t2), reduce over wave's a-quarter.
    // C/D layout (verified): col = lane&15, row = (lane>>4)*4 + reg
    int rg = lane >> 4;
#pragma unroll
    for (int mt = 0; mt < 4; mt++) {
#pragma unroll
        for (int r = 0; r < 4; r++) {
            float v = 0.f;
#pragma unroll
            for (int nt = 0; nt < 4; nt++) {
                int a = wave * 64 + nt * 16 + col;
                float x = acc[mt][nt][r] + s_t1[a];
                v += s_wa[a] * fmaxf(x, 0.f);
            }
#pragma unroll
            for (int off = 1; off < 16; off <<= 1) v += __shfl_xor(v, off, 64);
            if (col == 0) atomicAdd(&s_logit[mt * 16 + rg * 4 + r], v);
        }
    }
    __syncthreads();

    // block-local online-softmax stats (wave 0 only: lane t holds logit t)
    if (tid < TM) {
        float l = s_logit[tid];
        bool valid = (t0 + tid) < len;
        float m = valid ? l : -1e30f;
#pragma unroll
        for (int off = 32; off; off >>= 1) m = fmaxf(m, __shfl_xor(m, off, 64));
        float w = valid ? __expf(l - m) : 0.f;
        sw[tid] = w;
        float s = w;
#pragma unroll
        for (int off = 32; off; off >>= 1) s += __shfl_xor(s, off, 64);
        if (tid == 0) {
            ms[(b * NBLK + blk) * 2]     = m;
            ms[(b * NBLK + blk) * 2 + 1] = s;
        }
        logits[(size_t)b * T_SZ + t0 + tid] = l;   // raw logit (masked later)
    }
    __syncthreads();

    // partial representation: P[d] = sum_t sw[t] * M[t,d]; A-tile is L2-hot.
    int d = 2 * tid;
    int nv = min(TM, len - t0);
    float p0 = 0.f, p1 = 0.f;
#pragma unroll 4
    for (int t = 0; t < nv; t++) {
        float w = sw[t];
        float2 mv = *(const float2*)(Abase + (size_t)t * DK + d);
        p0 = fmaf(w, mv.x, p0);
        p1 = fmaf(w, mv.y, p1);
    }
    float* Pb = P + ((size_t)(b * NBLK + blk)) * DV;
    Pb[d]     = p0;
    Pb[d + 1] = p1;
}

// ---------------------------------------------------------------------------
// Kernel 2: combine partials (exact flash-style merge) + write rep + normalize
// attention row. One block per batch row, 1024 threads.
// ---------------------------------------------------------------------------
__global__ __launch_bounds__(1024) void combine_kernel(
    const int* __restrict__ lens, const float* __restrict__ P,
    const float* __restrict__ ms, float* __restrict__ rep,
    float* __restrict__ attn) {
    int b = blockIdx.x, tid = threadIdx.x;
    int len = get_len(lens, b);
    int nblk = (len + TM - 1) / TM;

    __shared__ float sm[NBLK];      // local maxes
    __shared__ float sscale[NBLK];  // exp(m_blk - m)
    __shared__ float s_gm, s_gS;

    if (tid < NBLK) {
        if (tid < nblk) {
            sm[tid]     = ms[(b * NBLK + tid) * 2];
            sscale[tid] = ms[(b * NBLK + tid) * 2 + 1];   // temp: s_blk
        } else {
            sm[tid] = -1e30f; sscale[tid] = 0.f;
        }
    }
    __syncthreads();
    if (tid < NBLK) {   // single wave... NBLK=64 -> exactly wave 0
        float m = sm[tid];
#pragma unroll
        for (int off = 32; off; off >>= 1) m = fmaxf(m, __shfl_xor(m, off, 64));
        float sc = (tid < nblk) ? __expf(sm[tid] - m) : 0.f;
        float S = sc * sscale[tid];
#pragma unroll
        for (int off = 32; off; off >>= 1) S += __shfl_xor(S, off, 64);
        sscale[tid] = sc;
        if (tid == 0) { s_gm = m; s_gS = S; }
    }
    __syncthreads();
    float m = s_gm;
    float invS = 1.f / s_gS;

    // rep[b,d] = invS * sum_blk sscale[blk] * P[b,blk,d]
    if (tid < DV) {
        float acc = 0.f;
        const float* Pb = P + (size_t)b * NBLK * DV + tid;
        for (int blk = 0; blk < nblk; blk++)
            acc += sscale[blk] * Pb[(size_t)blk * DV];
        rep[b * DV + tid] = acc * invS;
    }

    // normalize attention row
    float* row = attn + (size_t)b * T_SZ;
#pragma unroll
    for (int i = 0; i < T_SZ / 1024; i++) {
        int t = tid + i * 1024;
        float l = row[t];
        row[t] = (t < len) ? __expf(l - m) * invS : 0.f;
    }
}

// ---------------------------------------------------------------------------
extern "C" void kernel_launch(void* const* d_in, const int* in_sizes, int n_in,
                              void* d_out, int out_size, void* d_ws, size_t ws_size,
                              hipStream_t stream) {
    const float* vector = (const float*)d_in[0];
    const float* matrix = (const float*)d_in[1];
    const int*   lens   = (const int*)d_in[2];
    const float* wvec   = (const float*)d_in[3];
    const float* wmat   = (const float*)d_in[4];
    const float* wattn  = (const float*)d_in[5];

    float* rep  = (float*)d_out;            // [32, 512]
    float* attn = rep + B_SZ * DV;          // [32, 4096] raw logits -> normalized

    char* ws = (char*)d_ws;
    float*  t1      = (float*)ws;                        // 32 KB
    __bf16* wmat_bf = (__bf16*)(ws + 32768);             // 256 KB
    float*  P       = (float*)(ws + 32768 + 262144);     // 32*64*512 f32 = 4 MB
    float*  ms      = (float*)(ws + 32768 + 262144 + 4194304);  // 32*64*2 f32 = 16 KB

    setup_kernel<<<dim3(160), 256, 0, stream>>>(wmat, wmat_bf, vector, wvec, t1);
    logits_kernel<<<dim3(NBLK, B_SZ), 256, 0, stream>>>(matrix, wmat_bf, t1, wattn,
                                                        lens, attn, P, ms);
    combine_kernel<<<dim3(B_SZ), 1024, 0, stream>>>(lens, P, ms, rep, attn);
}